// Round 12
// baseline (85.655 us; speedup 1.0000x reference)
//
#include <hip/hip_runtime.h>

#define D_FEAT   128
#define MAXBLK   2048   // 8 blocks/CU x 256 CUs upper bound
#define EPT_MAX  4      // G >= 782 covers 800K edges: 782*256*4 = 800,768

// K1: per-node projection, 8-lane group per node (32 nodes / 256-thread block).
// pu[n] = h[n].Wu + b ; pv[n] = h[n].Wv
// First 16 blocks also zero the K2 sync arrays (arrive[2048] + donef[2048]).
__global__ __launch_bounds__(256) void proj_kernel(
    const float* __restrict__ h,
    const float* __restrict__ W,
    const float* __restrict__ bptr,
    float* __restrict__ pu,
    float* __restrict__ pv,
    unsigned* __restrict__ sync_all,   // [2*MAXBLK]: arrive | donef
    int n_nodes)
{
    const int z = blockIdx.x * 256 + threadIdx.x;
    if (z < 2 * MAXBLK) sync_all[z] = 0u;

    const int t    = threadIdx.x & 7;
    const int node = blockIdx.x * 32 + (threadIdx.x >> 3);
    if (node >= n_nodes) return;

    const float4* W4 = (const float4*)W;
    float4 wu[4], wv[4];
    #pragma unroll
    for (int j = 0; j < 4; ++j) {
        wu[j] = W4[j * 8 + t];          // L1-resident after first wave
        wv[j] = W4[32 + j * 8 + t];
    }

    const float4* h4 = (const float4*)(h + (size_t)node * D_FEAT);
    float4 hv[4];
    #pragma unroll
    for (int j = 0; j < 4; ++j) hv[j] = h4[j * 8 + t];   // 64 B/lane in flight

    float su = 0.f, sv = 0.f;
    #pragma unroll
    for (int j = 0; j < 4; ++j) {
        su += hv[j].x*wu[j].x + hv[j].y*wu[j].y + hv[j].z*wu[j].z + hv[j].w*wu[j].w;
        sv += hv[j].x*wv[j].x + hv[j].y*wv[j].y + hv[j].z*wv[j].z + hv[j].w*wv[j].w;
    }
    #pragma unroll
    for (int off = 4; off > 0; off >>= 1) {   // xor 4,2,1: stays in 8-lane group
        su += __shfl_xor(su, off, 64);
        sv += __shfl_xor(sv, off, 64);
    }
    if (t == 0) {
        pu[node] = su + bptr[0];   // bias folded in: score = pu[src]+pv[dst]
        pv[node] = sv;
    }
}

// K2 fused: scores in registers -> per-block partial + arrival flag (distinct
// slots) -> block 0 reduces and FANS OUT per-block done flags (each spinner
// polls its OWN word — no single-line hot spot) -> normalize from registers.
__global__ __launch_bounds__(256, 8) void fused_score_norm_kernel(
    const int*   __restrict__ src,
    const int*   __restrict__ dst,
    const float* __restrict__ pu,
    const float* __restrict__ pv,
    float*       __restrict__ out,
    unsigned long long* __restrict__ partials,  // [MAXBLK] packed (maxbits<<32|minbits)
    unsigned long long* __restrict__ gcell,     // packed (invbits<<32|minbits)
    unsigned* __restrict__ arrive,              // [MAXBLK]
    unsigned* __restrict__ donef,               // [MAXBLK]
    int n_edges)
{
    const int G      = gridDim.x;
    const int tid    = blockIdx.x * 256 + threadIdx.x;
    const int stride = G * 256;

    // ---- phase A: scores in registers (static indexing only) ----
    float sc[EPT_MAX];
    float vmin =  3.4028235e38f;
    float vmax = -3.4028235e38f;
    #pragma unroll
    for (int k = 0; k < EPT_MAX; ++k) {
        const int e = tid + k * stride;
        float s = 0.f;
        if (e < n_edges) {
            s = pu[src[e]] + pv[dst[e]];   // pu/pv: 800 KB, L2-resident
            vmin = fminf(vmin, s);
            vmax = fmaxf(vmax, s);
        }
        sc[k] = s;
    }
    #pragma unroll
    for (int off = 32; off > 0; off >>= 1) {
        vmin = fminf(vmin, __shfl_xor(vmin, off, 64));
        vmax = fmaxf(vmax, __shfl_xor(vmax, off, 64));
    }
    __shared__ float smin[4], smax[4];
    __shared__ unsigned g_lo, g_hi;
    const int w = threadIdx.x >> 6;
    if ((threadIdx.x & 63) == 0) { smin[w] = vmin; smax[w] = vmax; }
    __syncthreads();

    // ---- publish per-block partial + arrival flag (distinct slots) ----
    if (threadIdx.x == 0) {
        const float a = fminf(fminf(smin[0], smin[1]), fminf(smin[2], smin[3]));
        const float m = fmaxf(fmaxf(smax[0], smax[1]), fmaxf(smax[2], smax[3]));
        const unsigned long long p =
            ((unsigned long long)__float_as_uint(m) << 32) | __float_as_uint(a);
        __hip_atomic_exchange(&partials[blockIdx.x], p,
                              __ATOMIC_RELEASE, __HIP_MEMORY_SCOPE_AGENT);
        __hip_atomic_store(&arrive[blockIdx.x], 1u,
                           __ATOMIC_RELEASE, __HIP_MEMORY_SCOPE_AGENT);
    }

    if (blockIdx.x == 0) {
        // ---- reducer: poll G arrival flags (distinct addrs, <=8/thread) ----
        const int per = (G + 255) >> 8;
        float a =  3.4028235e38f;
        float m = -3.4028235e38f;
        for (int j = 0; j < per; ++j) {
            const int idx = threadIdx.x + j * 256;
            if (idx < G) {
                while (__hip_atomic_load(&arrive[idx], __ATOMIC_RELAXED,
                                         __HIP_MEMORY_SCOPE_AGENT) == 0u)
                    __builtin_amdgcn_s_sleep(1);
                const unsigned long long p = __hip_atomic_load(&partials[idx],
                                         __ATOMIC_ACQUIRE, __HIP_MEMORY_SCOPE_AGENT);
                a = fminf(a, __uint_as_float((unsigned)(p & 0xFFFFFFFFull)));
                m = fmaxf(m, __uint_as_float((unsigned)(p >> 32)));
            }
        }
        #pragma unroll
        for (int off = 32; off > 0; off >>= 1) {
            a = fminf(a, __shfl_xor(a, off, 64));
            m = fmaxf(m, __shfl_xor(m, off, 64));
        }
        if ((threadIdx.x & 63) == 0) { smin[w] = a; smax[w] = m; }
        __syncthreads();
        if (threadIdx.x == 0) {
            const float mn  = fminf(fminf(smin[0], smin[1]), fminf(smin[2], smin[3]));
            const float mx  = fmaxf(fmaxf(smax[0], smax[1]), fmaxf(smax[2], smax[3]));
            const float inv = 1.0f / (mx - mn);
            const unsigned long long gv =
                ((unsigned long long)__float_as_uint(inv) << 32) | __float_as_uint(mn);
            __hip_atomic_exchange(gcell, gv,
                                  __ATOMIC_RELEASE, __HIP_MEMORY_SCOPE_AGENT);
            g_lo = (unsigned)(gv & 0xFFFFFFFFull);
            g_hi = (unsigned)(gv >> 32);
        }
        __syncthreads();            // gcell store ordered before the fan-out
        // ---- fan-out: per-block done flags, 8 distinct stores per thread ----
        for (int j = 0; j < per; ++j) {
            const int idx = threadIdx.x + j * 256;
            if (idx < G)
                __hip_atomic_store(&donef[idx], 1u,
                                   __ATOMIC_RELEASE, __HIP_MEMORY_SCOPE_AGENT);
        }
    } else {
        // ---- each block spins on ITS OWN word — no shared hot line ----
        if (threadIdx.x == 0) {
            while (__hip_atomic_load(&donef[blockIdx.x], __ATOMIC_RELAXED,
                                     __HIP_MEMORY_SCOPE_AGENT) == 0u)
                __builtin_amdgcn_s_sleep(2);
            const unsigned long long gv = __hip_atomic_load(gcell,
                                  __ATOMIC_ACQUIRE, __HIP_MEMORY_SCOPE_AGENT);
            g_lo = (unsigned)(gv & 0xFFFFFFFFull);
            g_hi = (unsigned)(gv >> 32);
        }
        __syncthreads();
    }

    // ---- normalize register-held scores, single coalesced write ----
    const float mn  = __uint_as_float(g_lo);
    const float inv = __uint_as_float(g_hi);
    #pragma unroll
    for (int k = 0; k < EPT_MAX; ++k) {
        const int e = tid + k * stride;
        if (e < n_edges) out[e] = (sc[k] - mn) * inv;
    }
}

extern "C" void kernel_launch(void* const* d_in, const int* in_sizes, int n_in,
                              void* d_out, int out_size, void* d_ws, size_t ws_size,
                              hipStream_t stream) {
    const float* h   = (const float*)d_in[0];
    const int*   src = (const int*)d_in[1];
    const int*   dst = (const int*)d_in[2];
    const float* W   = (const float*)d_in[3];
    const float* b   = (const float*)d_in[4];
    float* out = (float*)d_out;

    const int n_nodes = in_sizes[0] / D_FEAT;
    const int n_edges = in_sizes[1];

    // ws layout (2*n_nodes floats = 800 KB, 8B-aligned):
    //   pu | pv | partials[MAXBLK] (ull) | gcell (ull) | arrive[MAXBLK] | donef[MAXBLK]
    float* ws = (float*)d_ws;
    float* pu = ws;
    float* pv = ws + n_nodes;
    unsigned long long* partials = (unsigned long long*)(ws + 2 * n_nodes);
    unsigned long long* gcell    = partials + MAXBLK;
    unsigned*           sync_all = (unsigned*)(gcell + 1);
    unsigned*           arrive   = sync_all;
    unsigned*           donef    = sync_all + MAXBLK;

    // K1: 32 nodes / block -> 3125 blocks (also zeroes arrive+donef)
    {
        const int blocks = (n_nodes + 31) / 32;
        proj_kernel<<<blocks, 256, 0, stream>>>(h, W, b, pu, pv, sync_all, n_nodes);
    }
    // K2: fused. Grid = max co-resident blocks (occupancy-queried, full TLP).
    {
        int perCU = 0;
        (void)hipOccupancyMaxActiveBlocksPerMultiprocessor(
            &perCU, (const void*)fused_score_norm_kernel, 256, 0);
        if (perCU < 4) perCU = 4;     // 1024 blocks: 24-VGPR/512B-LDS kernel, safe
        if (perCU > 8) perCU = 8;     // wave-slot ceiling
        int G = perCU * 256;
        if (G > MAXBLK) G = MAXBLK;
        fused_score_norm_kernel<<<G, 256, 0, stream>>>(
            src, dst, pu, pv, out, partials, gcell, arrive, donef, n_edges);
    }
}

// Round 13
// 37.210 us; speedup vs baseline: 2.3019x; 2.3019x over previous
//
#include <hip/hip_runtime.h>

#define D_FEAT  128
#define NSHARD  64     // atomic shards; 3125 blocks / 64 ~ 49-deep chains per cell

// Monotonic float -> uint map: order-preserving, so uint atomicMin/Max == float min/max.
__device__ __forceinline__ unsigned mapf(float f) {
    unsigned u = __float_as_uint(f);
    return (u & 0x80000000u) ? ~u : (u | 0x80000000u);
}
__device__ __forceinline__ float unmapf(unsigned u) {
    return (u & 0x80000000u) ? __uint_as_float(u & 0x7FFFFFFFu)
                             : __uint_as_float(~u);
}

// K1: per-node projection, 8-lane group per node (32 nodes / 256-thread block).
// pu[n] = h[n].Wu + b ; pv[n] = h[n].Wv
// Block 0 also re-inits the 2*NSHARD atomic cells (visible at dispatch boundary).
__global__ __launch_bounds__(256) void proj_kernel(
    const float* __restrict__ h,
    const float* __restrict__ W,
    const float* __restrict__ bptr,
    float* __restrict__ pu,
    float* __restrict__ pv,
    unsigned* __restrict__ cells,   // [0..63]=min cells, [64..127]=max cells
    int n_nodes)
{
    if (blockIdx.x == 0 && threadIdx.x < 2 * NSHARD)
        cells[threadIdx.x] = (threadIdx.x < NSHARD) ? 0xFFFFFFFFu : 0u;

    const int t    = threadIdx.x & 7;
    const int node = blockIdx.x * 32 + (threadIdx.x >> 3);
    if (node >= n_nodes) return;

    const float4* W4 = (const float4*)W;
    float4 wu[4], wv[4];
    #pragma unroll
    for (int j = 0; j < 4; ++j) {
        wu[j] = W4[j * 8 + t];          // L1-resident after first wave
        wv[j] = W4[32 + j * 8 + t];
    }

    const float4* h4 = (const float4*)(h + (size_t)node * D_FEAT);
    float4 hv[4];
    #pragma unroll
    for (int j = 0; j < 4; ++j) hv[j] = h4[j * 8 + t];   // 64 B/lane in flight

    float su = 0.f, sv = 0.f;
    #pragma unroll
    for (int j = 0; j < 4; ++j) {
        su += hv[j].x*wu[j].x + hv[j].y*wu[j].y + hv[j].z*wu[j].z + hv[j].w*wu[j].w;
        sv += hv[j].x*wv[j].x + hv[j].y*wv[j].y + hv[j].z*wv[j].z + hv[j].w*wv[j].w;
    }
    #pragma unroll
    for (int off = 4; off > 0; off >>= 1) {   // xor 4,2,1: stays in 8-lane group
        su += __shfl_xor(su, off, 64);
        sv += __shfl_xor(sv, off, 64);
    }
    if (t == 0) {
        pu[node] = su + bptr[0];   // bias folded in: score = pu[src]+pv[dst]
        pv[node] = sv;
    }
}

// K2: 1 edge/thread, 3125 blocks (max TLP — proven fastest gather regime).
// Raw score -> out. Block min/max -> SHARDED atomicMin/Max (~49-deep chains,
// issued at block retire; no single hot chain, no extra dispatch needed).
__global__ __launch_bounds__(256) void score_kernel(
    const int*   __restrict__ src,
    const int*   __restrict__ dst,
    const float* __restrict__ pu,
    const float* __restrict__ pv,
    float*       __restrict__ out,
    unsigned*    __restrict__ cells,
    int n_edges)
{
    const int i = blockIdx.x * blockDim.x + threadIdx.x;
    float vmin =  3.4028235e38f;
    float vmax = -3.4028235e38f;
    if (i < n_edges) {
        const float s = pu[src[i]] + pv[dst[i]];   // pu/pv: 800 KB, L2-resident
        out[i] = s;
        vmin = s;
        vmax = s;
    }
    #pragma unroll
    for (int off = 32; off > 0; off >>= 1) {
        vmin = fminf(vmin, __shfl_xor(vmin, off, 64));
        vmax = fmaxf(vmax, __shfl_xor(vmax, off, 64));
    }
    __shared__ float smin[4], smax[4];
    const int w = threadIdx.x >> 6;
    if ((threadIdx.x & 63) == 0) { smin[w] = vmin; smax[w] = vmax; }
    __syncthreads();
    if (threadIdx.x == 0) {
        const float a = fminf(fminf(smin[0], smin[1]), fminf(smin[2], smin[3]));
        const float m = fmaxf(fmaxf(smax[0], smax[1]), fmaxf(smax[2], smax[3]));
        const int shard = blockIdx.x & (NSHARD - 1);
        atomicMin(&cells[shard], mapf(a));
        atomicMax(&cells[NSHARD + shard], mapf(m));
    }
}

// K3: reduce the 128 cells once per block (first wave), then float4 normalize.
__global__ __launch_bounds__(256) void norm_kernel(
    float* __restrict__ out,
    const unsigned* __restrict__ cells,
    int n4, int n_edges)
{
    __shared__ float s_mn, s_inv;
    if (threadIdx.x < 64) {                       // first wave only
        float a = unmapf(cells[threadIdx.x]);             // min cells
        float m = unmapf(cells[NSHARD + threadIdx.x]);    // max cells
        #pragma unroll
        for (int off = 32; off > 0; off >>= 1) {
            a = fminf(a, __shfl_xor(a, off, 64));
            m = fmaxf(m, __shfl_xor(m, off, 64));
        }
        if (threadIdx.x == 0) { s_mn = a; s_inv = 1.0f / (m - a); }
    }
    __syncthreads();
    const float mn  = s_mn;
    const float inv = s_inv;

    const int i = blockIdx.x * blockDim.x + threadIdx.x;
    if (i >= n4) return;
    float4 v = ((const float4*)out)[i];
    v.x = (v.x - mn) * inv;
    v.y = (v.y - mn) * inv;
    v.z = (v.z - mn) * inv;
    v.w = (v.w - mn) * inv;
    ((float4*)out)[i] = v;
    if (i == n4 - 1) {
        for (int e = n4 * 4; e < n_edges; ++e)
            out[e] = (out[e] - mn) * inv;
    }
}

extern "C" void kernel_launch(void* const* d_in, const int* in_sizes, int n_in,
                              void* d_out, int out_size, void* d_ws, size_t ws_size,
                              hipStream_t stream) {
    const float* h   = (const float*)d_in[0];
    const int*   src = (const int*)d_in[1];
    const int*   dst = (const int*)d_in[2];
    const float* W   = (const float*)d_in[3];
    const float* b   = (const float*)d_in[4];
    float* out = (float*)d_out;

    const int n_nodes = in_sizes[0] / D_FEAT;
    const int n_edges = in_sizes[1];

    // workspace: pu[n_nodes], pv[n_nodes], cells[128] (uint)
    float* ws = (float*)d_ws;
    float* pu = ws;
    float* pv = ws + n_nodes;
    unsigned* cells = (unsigned*)(ws + 2 * n_nodes);

    // K1: 32 nodes / block -> 3125 blocks (also inits the atomic cells)
    {
        const int blocks = (n_nodes + 31) / 32;
        proj_kernel<<<blocks, 256, 0, stream>>>(h, W, b, pu, pv, cells, n_nodes);
    }
    // K2: 1 edge/thread -> 3125 blocks, sharded atomics
    {
        const int blocks = (n_edges + 255) / 256;   // 3125
        score_kernel<<<blocks, 256, 0, stream>>>(src, dst, pu, pv, out, cells, n_edges);
    }
    // K3: cell-reduce + normalize in place
    {
        const int n4 = n_edges >> 2;               // 200000
        const int blocks = (n4 + 255) / 256;       // 782
        norm_kernel<<<blocks, 256, 0, stream>>>(out, cells, n4, n_edges);
    }
}

// Round 14
// 29.326 us; speedup vs baseline: 2.9208x; 1.2689x over previous
//
#include <hip/hip_runtime.h>

#define D_FEAT 128

// ==== CHAMPION (R6 structure, 28.95 µs) ====
// 4 stream-ordered dispatches, no device-scope atomics anywhere, max-TLP gather.
// Session-verified design rules embodied here:
//  - projection first: h read exactly once (51.2 MB), edges touch only pu/pv (800 KB, L2)
//  - K2 at 1 edge/thread, 3125 blocks: TLP >> per-thread batching for uncoalesced gathers
//  - per-BLOCK min/max partials to distinct addresses; single tiny reduce dispatch
//  - no global atomics (same-address chains cost ~10-30ns each, serialized)
//  - no single-kernel global barrier (>=40 µs on MI355X across 3 topologies)

// K1: per-node projection, 8-lane group per node (32 nodes / 256-thread block).
// pu[n] = h[n].Wu + b ; pv[n] = h[n].Wv
__global__ __launch_bounds__(256) void proj_kernel(
    const float* __restrict__ h,
    const float* __restrict__ W,
    const float* __restrict__ bptr,
    float* __restrict__ pu,
    float* __restrict__ pv,
    int n_nodes)
{
    const int t    = threadIdx.x & 7;
    const int node = blockIdx.x * 32 + (threadIdx.x >> 3);
    if (node >= n_nodes) return;

    const float4* W4 = (const float4*)W;
    float4 wu[4], wv[4];
    #pragma unroll
    for (int j = 0; j < 4; ++j) {
        wu[j] = W4[j * 8 + t];          // L1-resident after first wave
        wv[j] = W4[32 + j * 8 + t];
    }

    const float4* h4 = (const float4*)(h + (size_t)node * D_FEAT);
    float4 hv[4];
    #pragma unroll
    for (int j = 0; j < 4; ++j) hv[j] = h4[j * 8 + t];   // 64 B/lane in flight

    float su = 0.f, sv = 0.f;
    #pragma unroll
    for (int j = 0; j < 4; ++j) {
        su += hv[j].x*wu[j].x + hv[j].y*wu[j].y + hv[j].z*wu[j].z + hv[j].w*wu[j].w;
        sv += hv[j].x*wv[j].x + hv[j].y*wv[j].y + hv[j].z*wv[j].z + hv[j].w*wv[j].w;
    }
    #pragma unroll
    for (int off = 4; off > 0; off >>= 1) {   // xor 4,2,1: stays in 8-lane group
        su += __shfl_xor(su, off, 64);
        sv += __shfl_xor(sv, off, 64);
    }
    if (t == 0) {
        pu[node] = su + bptr[0];   // bias folded in: score = pu[src]+pv[dst]
        pv[node] = sv;
    }
}

// K2: 1 edge/thread, 3125 blocks (max TLP). Raw score -> out.
// Per-block min/max partials to DISTINCT addresses — no global atomics.
__global__ __launch_bounds__(256) void score_kernel(
    const int*   __restrict__ src,
    const int*   __restrict__ dst,
    const float* __restrict__ pu,
    const float* __restrict__ pv,
    float*       __restrict__ out,
    float*       __restrict__ pmin,
    float*       __restrict__ pmax,
    int n_edges)
{
    const int i = blockIdx.x * blockDim.x + threadIdx.x;
    float vmin =  3.4028235e38f;
    float vmax = -3.4028235e38f;
    if (i < n_edges) {
        const float s = pu[src[i]] + pv[dst[i]];   // pu/pv: 800 KB, L2-resident
        out[i] = s;
        vmin = s;
        vmax = s;
    }
    #pragma unroll
    for (int off = 32; off > 0; off >>= 1) {
        vmin = fminf(vmin, __shfl_xor(vmin, off, 64));
        vmax = fmaxf(vmax, __shfl_xor(vmax, off, 64));
    }
    __shared__ float smin[4], smax[4];
    const int w = threadIdx.x >> 6;
    if ((threadIdx.x & 63) == 0) { smin[w] = vmin; smax[w] = vmax; }
    __syncthreads();
    if (threadIdx.x == 0) {
        pmin[blockIdx.x] = fminf(fminf(smin[0], smin[1]), fminf(smin[2], smin[3]));
        pmax[blockIdx.x] = fmaxf(fmaxf(smax[0], smax[1]), fmaxf(smax[2], smax[3]));
    }
}

// K3: one 1024-thread block reduces the 3125 partial pairs -> g[0]=min, g[1]=max.
__global__ __launch_bounds__(1024) void minmax_reduce_kernel(
    const float* __restrict__ pmin,
    const float* __restrict__ pmax,
    float* __restrict__ g,
    int n)
{
    float vmin =  3.4028235e38f;
    float vmax = -3.4028235e38f;
    for (int i = threadIdx.x; i < n; i += 1024) {
        vmin = fminf(vmin, pmin[i]);
        vmax = fmaxf(vmax, pmax[i]);
    }
    #pragma unroll
    for (int off = 32; off > 0; off >>= 1) {
        vmin = fminf(vmin, __shfl_xor(vmin, off, 64));
        vmax = fmaxf(vmax, __shfl_xor(vmax, off, 64));
    }
    __shared__ float smin[16], smax[16];
    const int w = threadIdx.x >> 6;
    if ((threadIdx.x & 63) == 0) { smin[w] = vmin; smax[w] = vmax; }
    __syncthreads();
    if (threadIdx.x == 0) {
        float a = smin[0], m = smax[0];
        #pragma unroll
        for (int k = 1; k < 16; ++k) { a = fminf(a, smin[k]); m = fmaxf(m, smax[k]); }
        g[0] = a;
        g[1] = m;
    }
}

// K4: in-place normalize, float4, 1 vec4/thread (782 blocks).
__global__ __launch_bounds__(256) void norm_kernel(
    float* __restrict__ out,
    const float* __restrict__ g,
    int n4, int n_edges)
{
    const int i = blockIdx.x * blockDim.x + threadIdx.x;
    if (i >= n4) return;
    const float mn  = g[0];
    const float inv = 1.0f / (g[1] - mn);
    float4 v = ((const float4*)out)[i];
    v.x = (v.x - mn) * inv;
    v.y = (v.y - mn) * inv;
    v.z = (v.z - mn) * inv;
    v.w = (v.w - mn) * inv;
    ((float4*)out)[i] = v;
    if (i == n4 - 1) {
        for (int e = n4 * 4; e < n_edges; ++e)
            out[e] = (out[e] - mn) * inv;
    }
}

extern "C" void kernel_launch(void* const* d_in, const int* in_sizes, int n_in,
                              void* d_out, int out_size, void* d_ws, size_t ws_size,
                              hipStream_t stream) {
    const float* h   = (const float*)d_in[0];
    const int*   src = (const int*)d_in[1];
    const int*   dst = (const int*)d_in[2];
    const float* W   = (const float*)d_in[3];
    const float* b   = (const float*)d_in[4];
    float* out = (float*)d_out;

    const int n_nodes = in_sizes[0] / D_FEAT;
    const int n_edges = in_sizes[1];

    const int blk2 = (n_edges + 255) / 256;    // 3125

    // workspace: pu[n_nodes], pv[n_nodes], pmin[blk2], pmax[blk2], g[2]
    float* ws   = (float*)d_ws;
    float* pu   = ws;
    float* pv   = ws + n_nodes;
    float* pmin = ws + 2 * n_nodes;
    float* pmax = pmin + blk2;
    float* g    = pmax + blk2;

    // K1: 32 nodes / block -> 3125 blocks
    {
        const int blocks = (n_nodes + 31) / 32;
        proj_kernel<<<blocks, 256, 0, stream>>>(h, W, b, pu, pv, n_nodes);
    }
    // K2: 1 edge/thread -> 3125 blocks, no atomics
    score_kernel<<<blk2, 256, 0, stream>>>(src, dst, pu, pv, out, pmin, pmax, n_edges);
    // K3: single-block reduce of partials
    minmax_reduce_kernel<<<1, 1024, 0, stream>>>(pmin, pmax, g, blk2);
    // K4: normalize in place
    {
        const int n4 = n_edges >> 2;           // 200000
        const int blocks = (n4 + 255) / 256;   // 782
        norm_kernel<<<blocks, 256, 0, stream>>>(out, g, n4, n_edges);
    }
}